// Round 9
// baseline (457.846 us; speedup 1.0000x reference)
//
#include <hip/hip_runtime.h>

// ConvLSTM fused, MI355X (gfx950). T=16, B=4, C=32, H=W=64, HID=64.
// Round 17 = Round 16 resubmit (container infra failure, kernel audited
// clean: staging index chains, LDS layout consistency, output coverage,
// VGPR/LDS occupancy budget all verified by hand).
// Occupancy 8 -> 16 waves/CU. R10-R15 counters: MfmaUtil ~28%,
// VALUBusy ~30%, Occupancy 24.6% (2 waves/SIMD) and every intra-phase
// micro-opt neutral -> latency-bound at low occupancy (roofline table row
// 3). Wave tile halved to M=64xN=16: same 512 blocks / same 76.5KB LDS /
// 2 blocks/CU, but 512 thr (8 waves): wave w = y-row (w>>1), px-half
// (w&1). 4096 waves total, 4 waves/SIMD. Weight reg double-buffer dropped
// (R15: neutral) to fit <=128 VGPR. Everything else = R12/R15 base:
// async global_load_lds staging (dest linear), private lane-linear
// c_state, early c read, setprio on MFMA, combined bias.
// Fallback to verified fp32 kernel if ws_size too small.

#define TSTEPS 16
#define BATCH  4
#define CX     32
#define HID    64
#define HW     64
#define PW     66
#define QS     528     // shorts per q-slice row  = PW*8
#define XROW   2112    // shorts per x row  = 4*QS
#define HROW   4224    // shorts per h row  = 8*QS
#define LROW   1088    // shorts per staged LDS row segment = 4*34*8
#define SROWS  6       // staged rows per block (4 outputs + 2 halo)

typedef short bf16x8 __attribute__((ext_vector_type(8)));
typedef float f32x4  __attribute__((ext_vector_type(4)));
typedef unsigned short u16x4 __attribute__((ext_vector_type(4)));

__device__ __forceinline__ float sigmoidf_(float x){ return 1.0f/(1.0f+__expf(-x)); }
__device__ __forceinline__ float tanhf_(float x){ return 1.0f - 2.0f/(__expf(2.0f*x)+1.0f); }

__device__ __forceinline__ unsigned short f2bf(float f){
  unsigned u = __float_as_uint(f);
  return (unsigned short)((u + 0x7FFFu + ((u>>16)&1u)) >> 16);
}
__device__ __forceinline__ float bf2f(unsigned short s){ return __uint_as_float(((unsigned)s)<<16); }

__device__ __forceinline__ void gload_lds16(const void* g, void* l){
  __builtin_amdgcn_global_load_lds(
      (const __attribute__((address_space(1))) void*)g,
      (__attribute__((address_space(3))) void*)l, 16, 0, 0);
}

// ---------------- prep kernels (once per call) ----------------

// weights, block-contiguous tap slices in lane-contiguous order:
// wxT[(tap*4+chunk)*2048 + (g*64 + q*16 + h16)*8 + c8]            (q=c>>3)
// whT[(tap*4+chunk)*4096 + kc*2048 + (g*64 + q*16 + h16)*8 + c8]  (kc=c>>5)
__global__ __launch_bounds__(256) void prep_w(
    const float* __restrict__ wx, const float* __restrict__ wh,
    unsigned short* __restrict__ wxT, unsigned short* __restrict__ whT)
{
  int idx = blockIdx.x*256 + threadIdx.x;
  if (idx < 9*256*64){
    int tap = idx / (256*64);
    int rem = idx - tap*(256*64);
    int o = rem >> 6, c = rem & 63;
    int g = o >> 6, chunk = (o >> 4) & 3, h16 = o & 15;
    int kc = c >> 5, cc = c & 31, q = cc >> 3, c8 = cc & 7;
    whT[(size_t)(tap*4 + chunk)*4096 + kc*2048 + (g*64 + q*16 + h16)*8 + c8] =
        f2bf(wh[(o*HID + c)*9 + tap]);
  }
  if (idx < 9*256*32){
    int tap = idx / (256*32);
    int rem = idx - tap*(256*32);
    int o = rem >> 5, c = rem & 31;
    int g = o >> 6, chunk = (o >> 4) & 3, h16 = o & 15;
    int q = c >> 3, c8 = c & 7;
    wxT[(size_t)(tap*4 + chunk)*2048 + (g*64 + q*16 + h16)*8 + c8] =
        f2bf(wx[(o*CX + c)*9 + tap]);
  }
}

// x [T*B, CX, 64, 64] fp32 -> xT [T*B][yp 66][q 4][xp 66][c8 8] bf16 hi/lo
__global__ __launch_bounds__(256) void prep_x(
    const float* __restrict__ x,
    unsigned short* __restrict__ xh, unsigned short* __restrict__ xl)
{
  __shared__ float tile[CX][HW];
  const int tb = blockIdx.x, yp = blockIdx.y, tid = threadIdx.x;
  const int y = yp - 1;
  const bool rowok = (y >= 0 && y < HW);
  if (rowok){
    const float* src = x + (size_t)tb*CX*HW*HW + y*HW;
    for (int i = tid; i < CX*HW; i += 256){
      int c = i >> 6, xc = i & 63;
      tile[c][xc] = src[(size_t)c*HW*HW + xc];
    }
  }
  __syncthreads();
  size_t base = ((size_t)tb*PW + yp)*XROW;
  for (int i = tid; i < PW*CX; i += 256){
    int xp = i >> 5, c = i & 31;
    int xg = xp - 1;
    float v = (rowok && xg >= 0 && xg < HW) ? tile[c][xg] : 0.f;
    unsigned short h = f2bf(v);
    size_t o = base + ((size_t)(c >> 3)*PW + xp)*8 + (c & 7);
    xh[o] = h;
    xl[o] = f2bf(v - bf2f(h));
  }
}

__global__ __launch_bounds__(256) void zero_ws(unsigned long long* p, size_t n64){
  size_t i = (size_t)blockIdx.x*256 + threadIdx.x;
  size_t stride = (size_t)gridDim.x*256;
  for (; i < n64; i += stride) p[i] = 0ull;
}

// ---------------- the MFMA step kernel ----------------
// grid (8 = chunk*2+xh, 16 = yslab, 4 = b) = 512 blocks; 512 thr = 8 waves.
// wave w: y = yslab*4 + (w>>1), px-half = w&1; wave tile M=64 x N=16.
// h layout (global): [b][yp 66][kcq 8][xp 66][c8 8] bf16 hi/lo.
// LDS: xs[kind 2][r 6][q 4][px 34][c8 8], hs[kind 2][r 6][kc 2][q 4][px 34][8]
// (both linear in the staging loop index -> global_load_lds legal).
// c_state: private layout [block 512][tid 512][r 4] fp32 (lane-linear).

#define MFMA(a,b,c) __builtin_amdgcn_mfma_f32_16x16x32_bf16((a),(b),(c),0,0,0)

template<int FIRST>
__global__ __launch_bounds__(512, 4) void step_mfma(
    const unsigned short* __restrict__ xTh, const unsigned short* __restrict__ xTl,
    const unsigned short* __restrict__ wxT, const unsigned short* __restrict__ whT,
    const unsigned short* __restrict__ hph, const unsigned short* __restrict__ hpl,
    unsigned short* __restrict__ hch, unsigned short* __restrict__ hcl,
    const float* __restrict__ bxb, const float* __restrict__ bhb,
    float* __restrict__ c_state,   // [512 blk][512 tid][4 r] fp32
    float* __restrict__ h_out,     // [B][HID][64][64] fp32 (d_out slice t)
    int t)
{
  __shared__ __attribute__((aligned(16))) short xs[2*SROWS*LROW];   // 25.5 KB
  __shared__ __attribute__((aligned(16))) short hs[2*2*SROWS*LROW]; // 51 KB

  const int tid  = threadIdx.x;       // 0..511
  const int lane = tid & 63;
  const int w    = tid >> 6;          // wave 0..7
  const int wy   = w >> 1;            // y row within slab 0..3
  const int wn   = w & 1;             // 16-px half within the 32-px group
  const int nn = lane & 15, q = lane >> 4;
  const int chunk = blockIdx.x >> 1, xh = blockIdx.x & 1;
  const int y0 = blockIdx.y * 4;
  const int b  = blockIdx.z;
  const int m0 = chunk * 16;
  const int y  = y0 + wy;
  const int tb = t*BATCH + b;
  const int wfo = (q*16 + nn)*8;      // weight fragment offset (shorts)

  // lane-linear private c slot: 4 floats (16B) per thread
  const size_t cslot =
      (((size_t)((blockIdx.z*16 + blockIdx.y)*8 + blockIdx.x))*512 + tid)*4;

  // ---- async stage x/h rows: LDS dest linear = i*16B; incremental decode ----
  {
    const size_t xbase = ((size_t)tb*PW + y0)*XROW;
    int px = tid % 34, j = tid / 34;            // i = j*34 + px invariant
#pragma unroll 1
    for (int i = tid; i < 2*SROWS*4*34; i += 512){
      const int qq = j & 3;
      const int r2 = j >> 2;
      const int kind = (r2 >= SROWS) ? 1 : 0;
      const int r  = r2 - kind*SROWS;
      const unsigned short* src = (kind ? xTl : xTh)
          + xbase + (size_t)r*XROW + qq*QS + (xh*32 + px)*8;
      gload_lds16(src, &xs[(size_t)i*8]);
      px += 2; j += 15; if (px >= 34){ px -= 34; ++j; }   // += 512 = 15*34+2
    }
  }
  if (!FIRST){
    const size_t hbase = ((size_t)b*PW + y0)*HROW;
    int px = tid % 34, j = tid / 34;
#pragma unroll 1
    for (int i = tid; i < 2*SROWS*8*34; i += 512){
      const int kcq = j & 7;
      const int r2  = j >> 3;
      const int kind = (r2 >= SROWS) ? 1 : 0;
      const int r  = r2 - kind*SROWS;
      const unsigned short* src = (kind ? hpl : hph)
          + hbase + (size_t)r*HROW + kcq*QS + (xh*32 + px)*8;
      gload_lds16(src, &hs[(size_t)i*8]);
      px += 2; j += 15; if (px >= 34){ px -= 34; ++j; }
    }
  }

  // ---- early c read: latency hides under the tap loop ----
  f32x4 cpre;
  if (!FIRST) cpre = *(const f32x4*)&c_state[cslot];
  else        cpre = (f32x4){0.f,0.f,0.f,0.f};

  f32x4 acc[4];
#pragma unroll
  for (int g = 0; g < 4; ++g) acc[g] = (f32x4){0.f, 0.f, 0.f, 0.f};

  __syncthreads();   // drains vmcnt(0): staging + c load complete

  // ---- tap loop: fully unrolled, single-buffered (R15: dbuf neutral) ----
#pragma unroll
  for (int tap = 0; tap < 9; ++tap){
    const int ky = tap / 3;
    const int kx = tap - ky*3;
    const int r0 = wy + ky;             // staged row index 0..5
    const int o  = (q*34 + wn*16 + kx + nn)*8;

    // weight fragments (global, L1/L2-resident after first tap/block)
    const unsigned short* wp = wxT + (size_t)(tap*4 + chunk)*2048 + wfo;
    bf16x8 ax[4];
#pragma unroll
    for (int g = 0; g < 4; ++g) ax[g] = *(const bf16x8*)(wp + g*512);

    // x fragments (LDS)
    bf16x8 bx0 = *(const bf16x8*)&xs[r0*LROW + o];
    bf16x8 bx1 = *(const bf16x8*)&xs[(SROWS + r0)*LROW + o];

    if (!FIRST){
      const unsigned short* hp = whT + (size_t)(tap*4 + chunk)*4096 + wfo;
      bf16x8 ah[2][4];
#pragma unroll
      for (int kc = 0; kc < 2; ++kc)
#pragma unroll
        for (int g = 0; g < 4; ++g) ah[kc][g] = *(const bf16x8*)(hp + kc*2048 + g*512);
      bf16x8 bh[2][2];   // [kind][kc]
#pragma unroll
      for (int kc = 0; kc < 2; ++kc){
        bh[0][kc] = *(const bf16x8*)&hs[(r0*2 + kc)*LROW + o];
        bh[1][kc] = *(const bf16x8*)&hs[((SROWS + r0)*2 + kc)*LROW + o];
      }
      __builtin_amdgcn_s_setprio(1);
#pragma unroll
      for (int g = 0; g < 4; ++g){
        acc[g] = MFMA(ax[g], bx0, acc[g]);
        acc[g] = MFMA(ax[g], bx1, acc[g]);
      }
#pragma unroll
      for (int kc = 0; kc < 2; ++kc)
#pragma unroll
        for (int g = 0; g < 4; ++g){
          acc[g] = MFMA(ah[kc][g], bh[0][kc], acc[g]);
          acc[g] = MFMA(ah[kc][g], bh[1][kc], acc[g]);
        }
      __builtin_amdgcn_s_setprio(0);
    } else {
      __builtin_amdgcn_s_setprio(1);
#pragma unroll
      for (int g = 0; g < 4; ++g){
        acc[g] = MFMA(ax[g], bx0, acc[g]);
        acc[g] = MFMA(ax[g], bx1, acc[g]);
      }
      __builtin_amdgcn_s_setprio(0);
    }
  }

  // ---- epilogue: LSTM update, register-local ----
  // D layout: col = lane&15 = n (x), row = q*4 + r (hid within chunk)
  f32x4 bv[4];
#pragma unroll
  for (int g = 0; g < 4; ++g){
    f32x4 ba = *(const f32x4*)&bxb[g*HID + m0 + 4*q];
    f32x4 bb = *(const f32x4*)&bhb[g*HID + m0 + 4*q];
    bv[g] = ba + bb;
  }
  const int kcE = chunk >> 1;                       // h-layout indices for this
  const int qhE = ((chunk & 1) << 1) | (q >> 1);    // lane's 4 hid values
  const int c8b = (q & 1) * 4;
  const int xg  = xh*32 + wn*16 + nn;

  f32x4 cn;
  float hn[4];
#pragma unroll
  for (int r = 0; r < 4; ++r){
    float iv = sigmoidf_(acc[0][r] + bv[0][r]);
    float fv = sigmoidf_(acc[1][r] + bv[1][r]);
    float gv = tanhf_  (acc[2][r] + bv[2][r]);
    float ov = sigmoidf_(acc[3][r] + bv[3][r]);
    float cnv = fv*cpre[r] + iv*gv;
    cn[r] = cnv;
    hn[r] = ov * tanhf_(cnv);
  }
  *(f32x4*)&c_state[cslot] = cn;
#pragma unroll
  for (int r = 0; r < 4; ++r)
    h_out[(((size_t)b*HID + m0 + 4*q + r)*HW + y)*HW + xg] = hn[r];
  {
    const size_t hoff = ((size_t)b*PW + (y+1))*HROW + (kcE*4 + qhE)*QS + (xg+1)*8 + c8b;
    u16x4 ph, pl;
#pragma unroll
    for (int r = 0; r < 4; ++r){
      unsigned short h = f2bf(hn[r]);
      ph[r] = h;
      pl[r] = f2bf(hn[r] - bf2f(h));
    }
    *(u16x4*)&hch[hoff] = ph;
    *(u16x4*)&hcl[hoff] = pl;
  }
}

// ---------------- fallback: fp32 kernel (verified round 3) ----------------

#define FCHUNK  8
#define FTILE_H 16
#define FROWS   (FTILE_H + 2)
#define FSTRIDE 68

__device__ __forceinline__ void do_chunk_f(
    float tile[FCHUNK][FROWS][FSTRIDE],
    const float* __restrict__ src,
    const float* __restrict__ wp0, const float* __restrict__ wp1,
    const float* __restrict__ wp2, const float* __restrict__ wp3,
    int gy0, int txg, int ty, int tid, float (&acc)[4][2][4])
{
  __syncthreads();
  for (int s = tid; s < FCHUNK * FROWS * 32; s += 128) {
    int c2 = s & 31;
    int rowid = s >> 5;
    int ic = rowid / FROWS;
    int r  = rowid - ic * FROWS;
    int gy = gy0 - 1 + r;
    if ((unsigned)gy < (unsigned)HW) {
      float2 v = *(const float2*)&src[(ic << 12) + (gy << 6) + (c2 << 1)];
      *(float2*)&tile[ic][r][2 + (c2 << 1)] = v;
    }
  }
  __syncthreads();
  for (int ic = 0; ic < FCHUNK; ++ic) {
    float w0[9], w1[9], w2[9], w3[9];
#pragma unroll
    for (int k = 0; k < 9; ++k) {
      w0[k] = wp0[ic*9+k]; w1[k] = wp1[ic*9+k];
      w2[k] = wp2[ic*9+k]; w3[k] = wp3[ic*9+k];
    }
    float rv[4][8];
#pragma unroll
    for (int rr = 0; rr < 4; ++rr) {
      const float* p = &tile[ic][2*ty+rr][4*txg];
      float4 a  = *(const float4*)p;
      float4 bb = *(const float4*)(p + 4);
      rv[rr][0]=a.x; rv[rr][1]=a.y; rv[rr][2]=a.z; rv[rr][3]=a.w;
      rv[rr][4]=bb.x; rv[rr][5]=bb.y; rv[rr][6]=bb.z; rv[rr][7]=bb.w;
    }
#pragma unroll
    for (int j = 0; j < 2; ++j)
#pragma unroll
      for (int dy = 0; dy < 3; ++dy)
#pragma unroll
        for (int qq = 0; qq < 4; ++qq)
#pragma unroll
          for (int dx = 0; dx < 3; ++dx) {
            float v = rv[j+dy][qq+dx+1];
            int k = dy*3+dx;
            acc[0][j][qq] = fmaf(v, w0[k], acc[0][j][qq]);
            acc[1][j][qq] = fmaf(v, w1[k], acc[1][j][qq]);
            acc[2][j][qq] = fmaf(v, w2[k], acc[2][j][qq]);
            acc[3][j][qq] = fmaf(v, w3[k], acc[3][j][qq]);
          }
  }
}

__global__ __launch_bounds__(128) void convlstm_step_f(
    const float* __restrict__ x_t, const float* __restrict__ h_prev,
    const float* __restrict__ w_x2h, const float* __restrict__ b_x2h,
    const float* __restrict__ w_h2h, const float* __restrict__ b_h2h,
    float* __restrict__ c_state, float* __restrict__ h_out, int first)
{
  __shared__ float tile[FCHUNK][FROWS][FSTRIDE];
  const int txg = threadIdx.x, ty = threadIdx.y;
  const int tid = ty*16 + txg;
  const int by = blockIdx.x, hc = blockIdx.y, b = blockIdx.z;
  const int gy0 = by * FTILE_H;
  {
    float2* p = (float2*)&tile[0][0][0];
    for (int i = tid; i < FCHUNK*FROWS*FSTRIDE/2; i += 128)
      p[i] = make_float2(0.f, 0.f);
  }
  float acc[4][2][4];
#pragma unroll
  for (int g = 0; g < 4; ++g)
#pragma unroll
    for (int j = 0; j < 2; ++j)
#pragma unroll
      for (int qq = 0; qq < 4; ++qq) acc[g][j][qq] = 0.f;
  {
    const float* wx0 = w_x2h + (size_t)(0*HID+hc)*CX*9;
    const float* wx1 = w_x2h + (size_t)(1*HID+hc)*CX*9;
    const float* wx2 = w_x2h + (size_t)(2*HID+hc)*CX*9;
    const float* wx3 = w_x2h + (size_t)(3*HID+hc)*CX*9;
    for (int c0 = 0; c0 < CX; c0 += FCHUNK)
      do_chunk_f(tile, x_t + ((size_t)(b*CX+c0) << 12),
                 wx0+c0*9, wx1+c0*9, wx2+c0*9, wx3+c0*9, gy0, txg, ty, tid, acc);
  }
  if (!first){
    const float* wh0 = w_h2h + (size_t)(0*HID+hc)*HID*9;
    const float* wh1 = w_h2h + (size_t)(1*HID+hc)*HID*9;
    const float* wh2 = w_h2h + (size_t)(2*HID+hc)*HID*9;
    const float* wh3 = w_h2h + (size_t)(3*HID+hc)*HID*9;
    for (int c0 = 0; c0 < HID; c0 += FCHUNK)
      do_chunk_f(tile, h_prev + ((size_t)(b*HID+c0) << 12),
                 wh0+c0*9, wh1+c0*9, wh2+c0*9, wh3+c0*9, gy0, txg, ty, tid, acc);
  }
  const float bi = b_x2h[0*HID+hc] + b_h2h[0*HID+hc];
  const float bf = b_x2h[1*HID+hc] + b_h2h[1*HID+hc];
  const float bg = b_x2h[2*HID+hc] + b_h2h[2*HID+hc];
  const float bo = b_x2h[3*HID+hc] + b_h2h[3*HID+hc];
#pragma unroll
  for (int j = 0; j < 2; ++j){
    const int row = gy0 + 2*ty + j;
    const int off = ((b*HID + hc)*HW + row)*HW + 4*txg;
    float4 cpv4 = make_float4(0.f,0.f,0.f,0.f);
    if (!first) cpv4 = *(const float4*)&c_state[off];
    float cn[4], hn[4];
    const float cpv[4] = {cpv4.x, cpv4.y, cpv4.z, cpv4.w};
#pragma unroll
    for (int qq = 0; qq < 4; ++qq){
      const float ig = sigmoidf_(acc[0][j][qq] + bi);
      const float fg = sigmoidf_(acc[1][j][qq] + bf);
      const float gg = tanhf_  (acc[2][j][qq] + bg);
      const float og = sigmoidf_(acc[3][j][qq] + bo);
      const float cnv = fg*cpv[qq] + ig*gg;
      cn[qq] = cnv;
      hn[qq] = og * tanhf_(cnv);
    }
    *(float4*)&c_state[off] = make_float4(cn[0],cn[1],cn[2],cn[3]);
    *(float4*)&h_out[off]   = make_float4(hn[0],hn[1],hn[2],hn[3]);
  }
}

// ---------------- launcher ----------------

extern "C" void kernel_launch(void* const* d_in, const int* in_sizes, int n_in,
                              void* d_out, int out_size, void* d_ws, size_t ws_size,
                              hipStream_t stream) {
  const float* x     = (const float*)d_in[0];
  const float* w_x2h = (const float*)d_in[1];
  const float* b_x2h = (const float*)d_in[2];
  const float* w_h2h = (const float*)d_in[3];
  const float* b_h2h = (const float*)d_in[4];
  float* out = (float*)d_out;

  // ws layout (256-aligned)
  size_t off = 0;
  auto alloc = [&](size_t bytes) -> char* {
    char* p = (char*)d_ws + off;
    off += (bytes + 255) & ~(size_t)255;
    return p;
  };
  float* c_state = (float*)alloc((size_t)512*512*4*4);                // 4 MB
  unsigned short* wxT = (unsigned short*)alloc((size_t)9*4*2048*2);   // 147 KB
  unsigned short* whT = (unsigned short*)alloc((size_t)9*4*4096*2);   // 295 KB
  const size_t hT_bytes = (size_t)BATCH*PW*HROW*2;                    // 2,230,272
  unsigned short* hA_hi = (unsigned short*)alloc(hT_bytes);
  unsigned short* hA_lo = (unsigned short*)alloc(hT_bytes);
  unsigned short* hB_hi = (unsigned short*)alloc(hT_bytes);
  unsigned short* hB_lo = (unsigned short*)alloc(hT_bytes);
  const size_t xT_bytes = (size_t)TSTEPS*BATCH*PW*XROW*2;             // 17,842,176
  unsigned short* xT_hi = (unsigned short*)alloc(xT_bytes);
  unsigned short* xT_lo = (unsigned short*)alloc(xT_bytes);
  const size_t need = off;

  const size_t x_step = (size_t)BATCH*CX*HW*HW;
  const size_t h_step = (size_t)BATCH*HID*HW*HW;

  if (need <= ws_size) {
    // ---- MFMA path ----
    prep_w<<<(9*256*HID + 255)/256, 256, 0, stream>>>(w_x2h, w_h2h, wxT, whT);
    prep_x<<<dim3(TSTEPS*BATCH, PW), 256, 0, stream>>>(x, xT_hi, xT_lo);
    zero_ws<<<1024, 256, 0, stream>>>((unsigned long long*)hA_hi, 4*hT_bytes/8);

    for (int t = 0; t < TSTEPS; ++t) {
      unsigned short* hp_hi = (t & 1) ? hA_hi : hB_hi;
      unsigned short* hp_lo = (t & 1) ? hA_lo : hB_lo;
      unsigned short* hc_hi = (t & 1) ? hB_hi : hA_hi;
      unsigned short* hc_lo = (t & 1) ? hB_lo : hA_lo;
      if (t == 0)
        step_mfma<1><<<dim3(8, 16, BATCH), 512, 0, stream>>>(
            xT_hi, xT_lo, wxT, whT, hp_hi, hp_lo, hc_hi, hc_lo,
            b_x2h, b_h2h, c_state, out + (size_t)t*h_step, t);
      else
        step_mfma<0><<<dim3(8, 16, BATCH), 512, 0, stream>>>(
            xT_hi, xT_lo, wxT, whT, hp_hi, hp_lo, hc_hi, hc_lo,
            b_x2h, b_h2h, c_state, out + (size_t)t*h_step, t);
    }
  } else {
    // ---- fallback fp32 path ----
    dim3 grid(HW / FTILE_H, HID, BATCH);
    dim3 block(16, 8);
    for (int t = 0; t < TSTEPS; ++t) {
      const float* x_t    = x + (size_t)t*x_step;
      const float* h_prev = (t == 0) ? x : out + (size_t)(t-1)*h_step;
      float* h_out        = out + (size_t)t*h_step;
      convlstm_step_f<<<grid, block, 0, stream>>>(
          x_t, h_prev, w_x2h, b_x2h, w_h2h, b_h2h, c_state, h_out, t == 0 ? 1 : 0);
    }
  }
}

// Round 10
// 412.354 us; speedup vs baseline: 1.1103x; 1.1103x over previous
//
#include <hip/hip_runtime.h>

// ConvLSTM fused, MI355X (gfx950). T=16, B=4, C=32, H=W=64, HID=64.
// Round 18: 2-chunks-per-block. R17 (N=16 tiles) doubled weight-L2 traffic
// (440 MB/step) chasing occupancy and regressed. This gets 16 waves/CU
// WITHOUT that: wave tile stays M=64xN=32 (2048 waves, 221 MB/step weight
// reads), but blocks carry 8 waves = 2 chunks x 4 y-rows. LDS unchanged
// (76.5 KB; x/h staging is chunk-independent) -> 2 blocks/CU = 16
// waves/CU (4/SIMD), and h/x staging redundancy halves: 256 blocks x
// 78 KB = 20 MB/step (was 40). Single-buffered tap loop (R15: prefetch
// neutral) to fit the 128-VGPR cap 4 waves/SIMD needs (R10 measured this
// body at 116 VGPR). Everything else = R12/R15 verified base: async
// global_load_lds staging (dest linear in i), incremental staging decode,
// private lane-linear c_state, early c read, setprio, combined bias.
// Fallback to verified fp32 kernel if ws_size too small.

#define TSTEPS 16
#define BATCH  4
#define CX     32
#define HID    64
#define HW     64
#define PW     66
#define QS     528     // shorts per q-slice row  = PW*8
#define XROW   2112    // shorts per x row  = 4*QS
#define HROW   4224    // shorts per h row  = 8*QS
#define LROW   1088    // shorts per staged LDS row segment = 4*34*8
#define SROWS  6       // staged rows per block (4 outputs + 2 halo)

typedef short bf16x8 __attribute__((ext_vector_type(8)));
typedef float f32x4  __attribute__((ext_vector_type(4)));
typedef unsigned short u16x4 __attribute__((ext_vector_type(4)));

__device__ __forceinline__ float sigmoidf_(float x){ return 1.0f/(1.0f+__expf(-x)); }
__device__ __forceinline__ float tanhf_(float x){ return 1.0f - 2.0f/(__expf(2.0f*x)+1.0f); }

__device__ __forceinline__ unsigned short f2bf(float f){
  unsigned u = __float_as_uint(f);
  return (unsigned short)((u + 0x7FFFu + ((u>>16)&1u)) >> 16);
}
__device__ __forceinline__ float bf2f(unsigned short s){ return __uint_as_float(((unsigned)s)<<16); }

__device__ __forceinline__ void gload_lds16(const void* g, void* l){
  __builtin_amdgcn_global_load_lds(
      (const __attribute__((address_space(1))) void*)g,
      (__attribute__((address_space(3))) void*)l, 16, 0, 0);
}

// ---------------- prep kernels (once per call) ----------------

// weights, block-contiguous tap slices in lane-contiguous order:
// wxT[(tap*4+chunk)*2048 + (g*64 + q*16 + h16)*8 + c8]            (q=c>>3)
// whT[(tap*4+chunk)*4096 + kc*2048 + (g*64 + q*16 + h16)*8 + c8]  (kc=c>>5)
__global__ __launch_bounds__(256) void prep_w(
    const float* __restrict__ wx, const float* __restrict__ wh,
    unsigned short* __restrict__ wxT, unsigned short* __restrict__ whT)
{
  int idx = blockIdx.x*256 + threadIdx.x;
  if (idx < 9*256*64){
    int tap = idx / (256*64);
    int rem = idx - tap*(256*64);
    int o = rem >> 6, c = rem & 63;
    int g = o >> 6, chunk = (o >> 4) & 3, h16 = o & 15;
    int kc = c >> 5, cc = c & 31, q = cc >> 3, c8 = cc & 7;
    whT[(size_t)(tap*4 + chunk)*4096 + kc*2048 + (g*64 + q*16 + h16)*8 + c8] =
        f2bf(wh[(o*HID + c)*9 + tap]);
  }
  if (idx < 9*256*32){
    int tap = idx / (256*32);
    int rem = idx - tap*(256*32);
    int o = rem >> 5, c = rem & 31;
    int g = o >> 6, chunk = (o >> 4) & 3, h16 = o & 15;
    int q = c >> 3, c8 = c & 7;
    wxT[(size_t)(tap*4 + chunk)*2048 + (g*64 + q*16 + h16)*8 + c8] =
        f2bf(wx[(o*CX + c)*9 + tap]);
  }
}

// x [T*B, CX, 64, 64] fp32 -> xT [T*B][yp 66][q 4][xp 66][c8 8] bf16 hi/lo
__global__ __launch_bounds__(256) void prep_x(
    const float* __restrict__ x,
    unsigned short* __restrict__ xh, unsigned short* __restrict__ xl)
{
  __shared__ float tile[CX][HW];
  const int tb = blockIdx.x, yp = blockIdx.y, tid = threadIdx.x;
  const int y = yp - 1;
  const bool rowok = (y >= 0 && y < HW);
  if (rowok){
    const float* src = x + (size_t)tb*CX*HW*HW + y*HW;
    for (int i = tid; i < CX*HW; i += 256){
      int c = i >> 6, xc = i & 63;
      tile[c][xc] = src[(size_t)c*HW*HW + xc];
    }
  }
  __syncthreads();
  size_t base = ((size_t)tb*PW + yp)*XROW;
  for (int i = tid; i < PW*CX; i += 256){
    int xp = i >> 5, c = i & 31;
    int xg = xp - 1;
    float v = (rowok && xg >= 0 && xg < HW) ? tile[c][xg] : 0.f;
    unsigned short h = f2bf(v);
    size_t o = base + ((size_t)(c >> 3)*PW + xp)*8 + (c & 7);
    xh[o] = h;
    xl[o] = f2bf(v - bf2f(h));
  }
}

__global__ __launch_bounds__(256) void zero_ws(unsigned long long* p, size_t n64){
  size_t i = (size_t)blockIdx.x*256 + threadIdx.x;
  size_t stride = (size_t)gridDim.x*256;
  for (; i < n64; i += stride) p[i] = 0ull;
}

// ---------------- the MFMA step kernel ----------------
// grid (4 = cp*2+xh, 16 = yslab, 4 = b) = 256 blocks; 512 thr = 8 waves.
// wave w: chunk = cp*2 + (w>>2), y = yslab*4 + (w&3); tile M=64 x N=32.
// h layout (global): [b][yp 66][kcq 8][xp 66][c8 8] bf16 hi/lo.
// LDS: xs[kind 2][r 6][q 4][px 34][c8 8], hs[kind 2][r 6][kc 2][q 4][px 34][8]
// (both linear in the staging loop index -> global_load_lds legal; both
// chunk-independent, shared by all 8 waves).
// c_state: private layout [block 256][tid 512][ns 2][r 4] fp32 (lane-linear).

#define MFMA(a,b,c) __builtin_amdgcn_mfma_f32_16x16x32_bf16((a),(b),(c),0,0,0)

template<int FIRST>
__global__ __launch_bounds__(512, 4) void step_mfma(
    const unsigned short* __restrict__ xTh, const unsigned short* __restrict__ xTl,
    const unsigned short* __restrict__ wxT, const unsigned short* __restrict__ whT,
    const unsigned short* __restrict__ hph, const unsigned short* __restrict__ hpl,
    unsigned short* __restrict__ hch, unsigned short* __restrict__ hcl,
    const float* __restrict__ bxb, const float* __restrict__ bhb,
    float* __restrict__ c_state,   // [256 blk][512 tid][2 ns][4 r] fp32
    float* __restrict__ h_out,     // [B][HID][64][64] fp32 (d_out slice t)
    int t)
{
  __shared__ __attribute__((aligned(16))) short xs[2*SROWS*LROW];   // 25.5 KB
  __shared__ __attribute__((aligned(16))) short hs[2*2*SROWS*LROW]; // 51 KB

  const int tid  = threadIdx.x;       // 0..511
  const int lane = tid & 63;
  const int w    = tid >> 6;          // wave 0..7
  const int chl  = w >> 2;            // chunk-local 0..1
  const int wy   = w & 3;             // y row within slab
  const int nn = lane & 15, q = lane >> 4;
  const int cp = blockIdx.x >> 1, xh = blockIdx.x & 1;
  const int chunk = cp*2 + chl;
  const int y0 = blockIdx.y * 4;
  const int b  = blockIdx.z;
  const int m0 = chunk * 16;
  const int y  = y0 + wy;
  const int tb = t*BATCH + b;
  const int wfo = (q*16 + nn)*8;      // weight fragment offset (shorts)

  // lane-linear private c slot: 8 floats (32B) per thread
  const size_t cslot =
      (((size_t)((blockIdx.z*16 + blockIdx.y)*4 + blockIdx.x))*512 + tid)*8;

  // ---- async stage x/h rows: LDS dest linear = i*16B; incremental decode ----
  {
    const size_t xbase = ((size_t)tb*PW + y0)*XROW;
    int px = tid % 34, j = tid / 34;            // i = j*34 + px invariant
#pragma unroll 1
    for (int i = tid; i < 2*SROWS*4*34; i += 512){
      const int qq = j & 3;
      const int r2 = j >> 2;
      const int kind = (r2 >= SROWS) ? 1 : 0;
      const int r  = r2 - kind*SROWS;
      const unsigned short* src = (kind ? xTl : xTh)
          + xbase + (size_t)r*XROW + qq*QS + (xh*32 + px)*8;
      gload_lds16(src, &xs[(size_t)i*8]);
      px += 2; j += 15; if (px >= 34){ px -= 34; ++j; }   // += 512 = 15*34+2
    }
  }
  if (!FIRST){
    const size_t hbase = ((size_t)b*PW + y0)*HROW;
    int px = tid % 34, j = tid / 34;
#pragma unroll 1
    for (int i = tid; i < 2*SROWS*8*34; i += 512){
      const int kcq = j & 7;
      const int r2  = j >> 3;
      const int kind = (r2 >= SROWS) ? 1 : 0;
      const int r  = r2 - kind*SROWS;
      const unsigned short* src = (kind ? hpl : hph)
          + hbase + (size_t)r*HROW + kcq*QS + (xh*32 + px)*8;
      gload_lds16(src, &hs[(size_t)i*8]);
      px += 2; j += 15; if (px >= 34){ px -= 34; ++j; }
    }
  }

  // ---- early c read: latency hides under the tap loop ----
  f32x4 cpre[2];
  if (!FIRST){
    cpre[0] = *(const f32x4*)&c_state[cslot];
    cpre[1] = *(const f32x4*)&c_state[cslot + 4];
  } else {
    cpre[0] = (f32x4){0.f,0.f,0.f,0.f};
    cpre[1] = (f32x4){0.f,0.f,0.f,0.f};
  }

  f32x4 acc[4][2];
#pragma unroll
  for (int g = 0; g < 4; ++g)
#pragma unroll
    for (int ns = 0; ns < 2; ++ns)
      acc[g][ns] = (f32x4){0.f, 0.f, 0.f, 0.f};

  __syncthreads();   // drains vmcnt(0): staging + c load complete

  // ---- tap loop: fully unrolled, single-buffered ----
#pragma unroll
  for (int tap = 0; tap < 9; ++tap){
    const int ky = tap / 3;
    const int kx = tap - ky*3;
    const int r0 = wy + ky;             // staged row index 0..5
    const int ps = kx + nn;

    // x2h: weights (global, L2-resident) + x fragments (LDS)
    {
      const unsigned short* wp = wxT + (size_t)(tap*4 + chunk)*2048 + wfo;
      bf16x8 ax[4];
#pragma unroll
      for (int g = 0; g < 4; ++g) ax[g] = *(const bf16x8*)(wp + g*512);
      bf16x8 bxf[2][2];   // [kind][ns]
#pragma unroll
      for (int ns = 0; ns < 2; ++ns){
        const int o = (q*34 + ns*16 + ps)*8;
        bxf[0][ns] = *(const bf16x8*)&xs[r0*LROW + o];
        bxf[1][ns] = *(const bf16x8*)&xs[(SROWS + r0)*LROW + o];
      }
      __builtin_amdgcn_s_setprio(1);
#pragma unroll
      for (int ns = 0; ns < 2; ++ns)
#pragma unroll
        for (int g = 0; g < 4; ++g){
          acc[g][ns] = MFMA(ax[g], bxf[0][ns], acc[g][ns]);
          acc[g][ns] = MFMA(ax[g], bxf[1][ns], acc[g][ns]);
        }
      __builtin_amdgcn_s_setprio(0);
    }

    // h2h
    if (!FIRST){
      const unsigned short* hp = whT + (size_t)(tap*4 + chunk)*4096 + wfo;
      bf16x8 ah[2][4];
#pragma unroll
      for (int kc = 0; kc < 2; ++kc)
#pragma unroll
        for (int g = 0; g < 4; ++g) ah[kc][g] = *(const bf16x8*)(hp + kc*2048 + g*512);
      bf16x8 bhf[2][2][2];   // [kind][kc][ns]
#pragma unroll
      for (int kc = 0; kc < 2; ++kc)
#pragma unroll
        for (int ns = 0; ns < 2; ++ns){
          const int o = (q*34 + ns*16 + ps)*8;
          bhf[0][kc][ns] = *(const bf16x8*)&hs[(r0*2 + kc)*LROW + o];
          bhf[1][kc][ns] = *(const bf16x8*)&hs[((SROWS + r0)*2 + kc)*LROW + o];
        }
      __builtin_amdgcn_s_setprio(1);
#pragma unroll
      for (int kc = 0; kc < 2; ++kc)
#pragma unroll
        for (int ns = 0; ns < 2; ++ns)
#pragma unroll
          for (int g = 0; g < 4; ++g){
            acc[g][ns] = MFMA(ah[kc][g], bhf[0][kc][ns], acc[g][ns]);
            acc[g][ns] = MFMA(ah[kc][g], bhf[1][kc][ns], acc[g][ns]);
          }
      __builtin_amdgcn_s_setprio(0);
    }
  }

  // ---- epilogue: LSTM update, register-local ----
  // D layout: col = lane&15 = n (x), row = q*4 + r (hid within chunk)
  f32x4 bv[4];
#pragma unroll
  for (int g = 0; g < 4; ++g){
    f32x4 ba = *(const f32x4*)&bxb[g*HID + m0 + 4*q];
    f32x4 bb = *(const f32x4*)&bhb[g*HID + m0 + 4*q];
    bv[g] = ba + bb;
  }
  const int kcE = chunk >> 1;                       // h-layout indices for this
  const int qhE = ((chunk & 1) << 1) | (q >> 1);    // lane's 4 hid values
  const int c8b = (q & 1) * 4;
#pragma unroll
  for (int ns = 0; ns < 2; ++ns){
    const int xg = xh*32 + ns*16 + nn;
    f32x4 cn;
    float hn[4];
#pragma unroll
    for (int r = 0; r < 4; ++r){
      float iv = sigmoidf_(acc[0][ns][r] + bv[0][r]);
      float fv = sigmoidf_(acc[1][ns][r] + bv[1][r]);
      float gv = tanhf_  (acc[2][ns][r] + bv[2][r]);
      float ov = sigmoidf_(acc[3][ns][r] + bv[3][r]);
      float cnv = fv*cpre[ns][r] + iv*gv;
      cn[r] = cnv;
      hn[r] = ov * tanhf_(cnv);
    }
    *(f32x4*)&c_state[cslot + ns*4] = cn;
#pragma unroll
    for (int r = 0; r < 4; ++r)
      h_out[(((size_t)b*HID + m0 + 4*q + r)*HW + y)*HW + xg] = hn[r];
    const size_t hoff = ((size_t)b*PW + (y+1))*HROW + (kcE*4 + qhE)*QS + (xg+1)*8 + c8b;
    u16x4 ph, pl;
#pragma unroll
    for (int r = 0; r < 4; ++r){
      unsigned short h = f2bf(hn[r]);
      ph[r] = h;
      pl[r] = f2bf(hn[r] - bf2f(h));
    }
    *(u16x4*)&hch[hoff] = ph;
    *(u16x4*)&hcl[hoff] = pl;
  }
}

// ---------------- fallback: fp32 kernel (verified round 3) ----------------

#define FCHUNK  8
#define FTILE_H 16
#define FROWS   (FTILE_H + 2)
#define FSTRIDE 68

__device__ __forceinline__ void do_chunk_f(
    float tile[FCHUNK][FROWS][FSTRIDE],
    const float* __restrict__ src,
    const float* __restrict__ wp0, const float* __restrict__ wp1,
    const float* __restrict__ wp2, const float* __restrict__ wp3,
    int gy0, int txg, int ty, int tid, float (&acc)[4][2][4])
{
  __syncthreads();
  for (int s = tid; s < FCHUNK * FROWS * 32; s += 128) {
    int c2 = s & 31;
    int rowid = s >> 5;
    int ic = rowid / FROWS;
    int r  = rowid - ic * FROWS;
    int gy = gy0 - 1 + r;
    if ((unsigned)gy < (unsigned)HW) {
      float2 v = *(const float2*)&src[(ic << 12) + (gy << 6) + (c2 << 1)];
      *(float2*)&tile[ic][r][2 + (c2 << 1)] = v;
    }
  }
  __syncthreads();
  for (int ic = 0; ic < FCHUNK; ++ic) {
    float w0[9], w1[9], w2[9], w3[9];
#pragma unroll
    for (int k = 0; k < 9; ++k) {
      w0[k] = wp0[ic*9+k]; w1[k] = wp1[ic*9+k];
      w2[k] = wp2[ic*9+k]; w3[k] = wp3[ic*9+k];
    }
    float rv[4][8];
#pragma unroll
    for (int rr = 0; rr < 4; ++rr) {
      const float* p = &tile[ic][2*ty+rr][4*txg];
      float4 a  = *(const float4*)p;
      float4 bb = *(const float4*)(p + 4);
      rv[rr][0]=a.x; rv[rr][1]=a.y; rv[rr][2]=a.z; rv[rr][3]=a.w;
      rv[rr][4]=bb.x; rv[rr][5]=bb.y; rv[rr][6]=bb.z; rv[rr][7]=bb.w;
    }
#pragma unroll
    for (int j = 0; j < 2; ++j)
#pragma unroll
      for (int dy = 0; dy < 3; ++dy)
#pragma unroll
        for (int qq = 0; qq < 4; ++qq)
#pragma unroll
          for (int dx = 0; dx < 3; ++dx) {
            float v = rv[j+dy][qq+dx+1];
            int k = dy*3+dx;
            acc[0][j][qq] = fmaf(v, w0[k], acc[0][j][qq]);
            acc[1][j][qq] = fmaf(v, w1[k], acc[1][j][qq]);
            acc[2][j][qq] = fmaf(v, w2[k], acc[2][j][qq]);
            acc[3][j][qq] = fmaf(v, w3[k], acc[3][j][qq]);
          }
  }
}

__global__ __launch_bounds__(128) void convlstm_step_f(
    const float* __restrict__ x_t, const float* __restrict__ h_prev,
    const float* __restrict__ w_x2h, const float* __restrict__ b_x2h,
    const float* __restrict__ w_h2h, const float* __restrict__ b_h2h,
    float* __restrict__ c_state, float* __restrict__ h_out, int first)
{
  __shared__ float tile[FCHUNK][FROWS][FSTRIDE];
  const int txg = threadIdx.x, ty = threadIdx.y;
  const int tid = ty*16 + txg;
  const int by = blockIdx.x, hc = blockIdx.y, b = blockIdx.z;
  const int gy0 = by * FTILE_H;
  {
    float2* p = (float2*)&tile[0][0][0];
    for (int i = tid; i < FCHUNK*FROWS*FSTRIDE/2; i += 128)
      p[i] = make_float2(0.f, 0.f);
  }
  float acc[4][2][4];
#pragma unroll
  for (int g = 0; g < 4; ++g)
#pragma unroll
    for (int j = 0; j < 2; ++j)
#pragma unroll
      for (int qq = 0; qq < 4; ++qq) acc[g][j][qq] = 0.f;
  {
    const float* wx0 = w_x2h + (size_t)(0*HID+hc)*CX*9;
    const float* wx1 = w_x2h + (size_t)(1*HID+hc)*CX*9;
    const float* wx2 = w_x2h + (size_t)(2*HID+hc)*CX*9;
    const float* wx3 = w_x2h + (size_t)(3*HID+hc)*CX*9;
    for (int c0 = 0; c0 < CX; c0 += FCHUNK)
      do_chunk_f(tile, x_t + ((size_t)(b*CX+c0) << 12),
                 wx0+c0*9, wx1+c0*9, wx2+c0*9, wx3+c0*9, gy0, txg, ty, tid, acc);
  }
  if (!first){
    const float* wh0 = w_h2h + (size_t)(0*HID+hc)*HID*9;
    const float* wh1 = w_h2h + (size_t)(1*HID+hc)*HID*9;
    const float* wh2 = w_h2h + (size_t)(2*HID+hc)*HID*9;
    const float* wh3 = w_h2h + (size_t)(3*HID+hc)*HID*9;
    for (int c0 = 0; c0 < HID; c0 += FCHUNK)
      do_chunk_f(tile, h_prev + ((size_t)(b*HID+c0) << 12),
                 wh0+c0*9, wh1+c0*9, wh2+c0*9, wh3+c0*9, gy0, txg, ty, tid, acc);
  }
  const float bi = b_x2h[0*HID+hc] + b_h2h[0*HID+hc];
  const float bf = b_x2h[1*HID+hc] + b_h2h[1*HID+hc];
  const float bg = b_x2h[2*HID+hc] + b_h2h[2*HID+hc];
  const float bo = b_x2h[3*HID+hc] + b_h2h[3*HID+hc];
#pragma unroll
  for (int j = 0; j < 2; ++j){
    const int row = gy0 + 2*ty + j;
    const int off = ((b*HID + hc)*HW + row)*HW + 4*txg;
    float4 cpv4 = make_float4(0.f,0.f,0.f,0.f);
    if (!first) cpv4 = *(const float4*)&c_state[off];
    float cn[4], hn[4];
    const float cpv[4] = {cpv4.x, cpv4.y, cpv4.z, cpv4.w};
#pragma unroll
    for (int qq = 0; qq < 4; ++qq){
      const float ig = sigmoidf_(acc[0][j][qq] + bi);
      const float fg = sigmoidf_(acc[1][j][qq] + bf);
      const float gg = tanhf_  (acc[2][j][qq] + bg);
      const float og = sigmoidf_(acc[3][j][qq] + bo);
      const float cnv = fg*cpv[qq] + ig*gg;
      cn[qq] = cnv;
      hn[qq] = og * tanhf_(cnv);
    }
    *(float4*)&c_state[off] = make_float4(cn[0],cn[1],cn[2],cn[3]);
    *(float4*)&h_out[off]   = make_float4(hn[0],hn[1],hn[2],hn[3]);
  }
}

// ---------------- launcher ----------------

extern "C" void kernel_launch(void* const* d_in, const int* in_sizes, int n_in,
                              void* d_out, int out_size, void* d_ws, size_t ws_size,
                              hipStream_t stream) {
  const float* x     = (const float*)d_in[0];
  const float* w_x2h = (const float*)d_in[1];
  const float* b_x2h = (const float*)d_in[2];
  const float* w_h2h = (const float*)d_in[3];
  const float* b_h2h = (const float*)d_in[4];
  float* out = (float*)d_out;

  // ws layout (256-aligned)
  size_t off = 0;
  auto alloc = [&](size_t bytes) -> char* {
    char* p = (char*)d_ws + off;
    off += (bytes + 255) & ~(size_t)255;
    return p;
  };
  float* c_state = (float*)alloc((size_t)256*512*8*4);                // 4 MB
  unsigned short* wxT = (unsigned short*)alloc((size_t)9*4*2048*2);   // 147 KB
  unsigned short* whT = (unsigned short*)alloc((size_t)9*4*4096*2);   // 295 KB
  const size_t hT_bytes = (size_t)BATCH*PW*HROW*2;                    // 2,230,272
  unsigned short* hA_hi = (unsigned short*)alloc(hT_bytes);
  unsigned short* hA_lo = (unsigned short*)alloc(hT_bytes);
  unsigned short* hB_hi = (unsigned short*)alloc(hT_bytes);
  unsigned short* hB_lo = (unsigned short*)alloc(hT_bytes);
  const size_t xT_bytes = (size_t)TSTEPS*BATCH*PW*XROW*2;             // 17,842,176
  unsigned short* xT_hi = (unsigned short*)alloc(xT_bytes);
  unsigned short* xT_lo = (unsigned short*)alloc(xT_bytes);
  const size_t need = off;

  const size_t x_step = (size_t)BATCH*CX*HW*HW;
  const size_t h_step = (size_t)BATCH*HID*HW*HW;

  if (need <= ws_size) {
    // ---- MFMA path ----
    prep_w<<<(9*256*HID + 255)/256, 256, 0, stream>>>(w_x2h, w_h2h, wxT, whT);
    prep_x<<<dim3(TSTEPS*BATCH, PW), 256, 0, stream>>>(x, xT_hi, xT_lo);
    zero_ws<<<1024, 256, 0, stream>>>((unsigned long long*)hA_hi, 4*hT_bytes/8);

    for (int t = 0; t < TSTEPS; ++t) {
      unsigned short* hp_hi = (t & 1) ? hA_hi : hB_hi;
      unsigned short* hp_lo = (t & 1) ? hA_lo : hB_lo;
      unsigned short* hc_hi = (t & 1) ? hB_hi : hA_hi;
      unsigned short* hc_lo = (t & 1) ? hB_lo : hA_lo;
      if (t == 0)
        step_mfma<1><<<dim3(4, 16, BATCH), 512, 0, stream>>>(
            xT_hi, xT_lo, wxT, whT, hp_hi, hp_lo, hc_hi, hc_lo,
            b_x2h, b_h2h, c_state, out + (size_t)t*h_step, t);
      else
        step_mfma<0><<<dim3(4, 16, BATCH), 512, 0, stream>>>(
            xT_hi, xT_lo, wxT, whT, hp_hi, hp_lo, hc_hi, hc_lo,
            b_x2h, b_h2h, c_state, out + (size_t)t*h_step, t);
    }
  } else {
    // ---- fallback fp32 path ----
    dim3 grid(HW / FTILE_H, HID, BATCH);
    dim3 block(16, 8);
    for (int t = 0; t < TSTEPS; ++t) {
      const float* x_t    = x + (size_t)t*x_step;
      const float* h_prev = (t == 0) ? x : out + (size_t)(t-1)*h_step;
      float* h_out        = out + (size_t)t*h_step;
      convlstm_step_f<<<grid, block, 0, stream>>>(
          x_t, h_prev, w_x2h, b_x2h, w_h2h, b_h2h, c_state, h_out, t == 0 ? 1 : 0);
    }
  }
}

// Round 11
// 326.243 us; speedup vs baseline: 1.4034x; 1.2640x over previous
//
#include <hip/hip_runtime.h>

// ConvLSTM fused, MI355X (gfx950). T=16, B=4, C=32, H=W=64, HID=64.
// Round 19: fp16 single precision replaces bf16 hi/lo decomposition.
//  R18 budget: MFMA ~6us/step is the largest component and sits AT its
//  hw floor -> shrink the floor. fp16 (10 mantissa bits, 2^-11) is MORE
//  accurate than the current mix (bf16 weights at 2^-9 dominate absmax
//  0.0059) while halving MFMA count (432->216/wave), staged bytes
//  (20->10 MB/step), LDS (76.5->38.25 KB), h traffic, prep_x work.
//  Accumulation stays fp32 (MFMA C/D). mfma_f32_16x16x32_f16 = same
//  shape/rate as bf16 variant; C/D layout dtype-independent.
//  Structure = R18 verified: 256 blocks x 512 thr (8 waves = 2 chunks x
//  4 y-rows), 2 blocks/CU, async global_load_lds staging (dest linear),
//  incremental staging decode, private lane-linear c_state, early c
//  read, setprio, combined bias.
// Fallback to verified fp32 kernel if ws_size too small.

#define TSTEPS 16
#define BATCH  4
#define CX     32
#define HID    64
#define HW     64
#define PW     66
#define QS     528     // shorts per q-slice row  = PW*8
#define XROW   2112    // shorts per x row  = 4*QS
#define HROW   4224    // shorts per h row  = 8*QS
#define LROW   1088    // shorts per staged LDS row segment = 4*34*8
#define SROWS  6       // staged rows per block (4 outputs + 2 halo)

typedef _Float16 f16x8 __attribute__((ext_vector_type(8)));
typedef float f32x4  __attribute__((ext_vector_type(4)));
typedef unsigned short u16x4 __attribute__((ext_vector_type(4)));

__device__ __forceinline__ float sigmoidf_(float x){ return 1.0f/(1.0f+__expf(-x)); }
__device__ __forceinline__ float tanhf_(float x){ return 1.0f - 2.0f/(__expf(2.0f*x)+1.0f); }

__device__ __forceinline__ unsigned short f2h(float f){
  return __builtin_bit_cast(unsigned short, (_Float16)f);
}

__device__ __forceinline__ void gload_lds16(const void* g, void* l){
  __builtin_amdgcn_global_load_lds(
      (const __attribute__((address_space(1))) void*)g,
      (__attribute__((address_space(3))) void*)l, 16, 0, 0);
}

// ---------------- prep kernels (once per call) ----------------

// weights (fp16 bits), block-contiguous tap slices in lane-contiguous order:
// wxT[(tap*4+chunk)*2048 + (g*64 + q*16 + h16)*8 + c8]            (q=c>>3)
// whT[(tap*4+chunk)*4096 + kc*2048 + (g*64 + q*16 + h16)*8 + c8]  (kc=c>>5)
__global__ __launch_bounds__(256) void prep_w(
    const float* __restrict__ wx, const float* __restrict__ wh,
    unsigned short* __restrict__ wxT, unsigned short* __restrict__ whT)
{
  int idx = blockIdx.x*256 + threadIdx.x;
  if (idx < 9*256*64){
    int tap = idx / (256*64);
    int rem = idx - tap*(256*64);
    int o = rem >> 6, c = rem & 63;
    int g = o >> 6, chunk = (o >> 4) & 3, h16 = o & 15;
    int kc = c >> 5, cc = c & 31, q = cc >> 3, c8 = cc & 7;
    whT[(size_t)(tap*4 + chunk)*4096 + kc*2048 + (g*64 + q*16 + h16)*8 + c8] =
        f2h(wh[(o*HID + c)*9 + tap]);
  }
  if (idx < 9*256*32){
    int tap = idx / (256*32);
    int rem = idx - tap*(256*32);
    int o = rem >> 5, c = rem & 31;
    int g = o >> 6, chunk = (o >> 4) & 3, h16 = o & 15;
    int q = c >> 3, c8 = c & 7;
    wxT[(size_t)(tap*4 + chunk)*2048 + (g*64 + q*16 + h16)*8 + c8] =
        f2h(wx[(o*CX + c)*9 + tap]);
  }
}

// x [T*B, CX, 64, 64] fp32 -> xT [T*B][yp 66][q 4][xp 66][c8 8] fp16
__global__ __launch_bounds__(256) void prep_x(
    const float* __restrict__ x, unsigned short* __restrict__ xT)
{
  __shared__ float tile[CX][HW];
  const int tb = blockIdx.x, yp = blockIdx.y, tid = threadIdx.x;
  const int y = yp - 1;
  const bool rowok = (y >= 0 && y < HW);
  if (rowok){
    const float* src = x + (size_t)tb*CX*HW*HW + y*HW;
    for (int i = tid; i < CX*HW; i += 256){
      int c = i >> 6, xc = i & 63;
      tile[c][xc] = src[(size_t)c*HW*HW + xc];
    }
  }
  __syncthreads();
  size_t base = ((size_t)tb*PW + yp)*XROW;
  for (int i = tid; i < PW*CX; i += 256){
    int xp = i >> 5, c = i & 31;
    int xg = xp - 1;
    float v = (rowok && xg >= 0 && xg < HW) ? tile[c][xg] : 0.f;
    xT[base + ((size_t)(c >> 3)*PW + xp)*8 + (c & 7)] = f2h(v);
  }
}

__global__ __launch_bounds__(256) void zero_ws(unsigned long long* p, size_t n64){
  size_t i = (size_t)blockIdx.x*256 + threadIdx.x;
  size_t stride = (size_t)gridDim.x*256;
  for (; i < n64; i += stride) p[i] = 0ull;
}

// ---------------- the MFMA step kernel ----------------
// grid (4 = cp*2+xh, 16 = yslab, 4 = b) = 256 blocks; 512 thr = 8 waves.
// wave w: chunk = cp*2 + (w>>2), y = yslab*4 + (w&3); tile M=64 x N=32.
// h layout (global): [b][yp 66][kcq 8][xp 66][c8 8] fp16.
// LDS: xs[r 6][q 4][px 34][c8 8], hs[r 6][kc 2][q 4][px 34][8]
// (both linear in the staging loop index -> global_load_lds legal; both
// chunk-independent, shared by all 8 waves). Total 38.25 KB.
// c_state: private layout [block 256][tid 512][ns 2][r 4] fp32 (lane-linear).

#define MFMA(a,b,c) __builtin_amdgcn_mfma_f32_16x16x32_f16((a),(b),(c),0,0,0)

template<int FIRST>
__global__ __launch_bounds__(512, 4) void step_mfma(
    const unsigned short* __restrict__ xT,
    const unsigned short* __restrict__ wxT, const unsigned short* __restrict__ whT,
    const unsigned short* __restrict__ hp, unsigned short* __restrict__ hc,
    const float* __restrict__ bxb, const float* __restrict__ bhb,
    float* __restrict__ c_state,   // [256 blk][512 tid][2 ns][4 r] fp32
    float* __restrict__ h_out,     // [B][HID][64][64] fp32 (d_out slice t)
    int t)
{
  __shared__ __attribute__((aligned(16))) short xs[SROWS*LROW];     // 12.75 KB
  __shared__ __attribute__((aligned(16))) short hs[2*SROWS*LROW];   // 25.5 KB

  const int tid  = threadIdx.x;       // 0..511
  const int lane = tid & 63;
  const int w    = tid >> 6;          // wave 0..7
  const int chl  = w >> 2;            // chunk-local 0..1
  const int wy   = w & 3;             // y row within slab
  const int nn = lane & 15, q = lane >> 4;
  const int cp = blockIdx.x >> 1, xh = blockIdx.x & 1;
  const int chunk = cp*2 + chl;
  const int y0 = blockIdx.y * 4;
  const int b  = blockIdx.z;
  const int m0 = chunk * 16;
  const int y  = y0 + wy;
  const int tb = t*BATCH + b;
  const int wfo = (q*16 + nn)*8;      // weight fragment offset (shorts)

  // lane-linear private c slot: 8 floats (32B) per thread
  const size_t cslot =
      (((size_t)((blockIdx.z*16 + blockIdx.y)*4 + blockIdx.x))*512 + tid)*8;

  // ---- async stage x/h rows: LDS dest linear = i*16B; incremental decode ----
  {
    const size_t xbase = ((size_t)tb*PW + y0)*XROW;
    int px = tid % 34, j = tid / 34;            // i = j*34 + px invariant
#pragma unroll 1
    for (int i = tid; i < SROWS*4*34; i += 512){     // 816 iters
      const int qq = j & 3;
      const int r  = j >> 2;
      const unsigned short* src = xT
          + xbase + (size_t)r*XROW + qq*QS + (xh*32 + px)*8;
      gload_lds16(src, &xs[(size_t)i*8]);
      px += 2; j += 15; if (px >= 34){ px -= 34; ++j; }   // += 512 = 15*34+2
    }
  }
  if (!FIRST){
    const size_t hbase = ((size_t)b*PW + y0)*HROW;
    int px = tid % 34, j = tid / 34;
#pragma unroll 1
    for (int i = tid; i < SROWS*8*34; i += 512){     // 1632 iters
      const int kcq = j & 7;
      const int r   = j >> 3;
      const unsigned short* src = hp
          + hbase + (size_t)r*HROW + kcq*QS + (xh*32 + px)*8;
      gload_lds16(src, &hs[(size_t)i*8]);
      px += 2; j += 15; if (px >= 34){ px -= 34; ++j; }
    }
  }

  // ---- early c read: latency hides under the tap loop ----
  f32x4 cpre[2];
  if (!FIRST){
    cpre[0] = *(const f32x4*)&c_state[cslot];
    cpre[1] = *(const f32x4*)&c_state[cslot + 4];
  } else {
    cpre[0] = (f32x4){0.f,0.f,0.f,0.f};
    cpre[1] = (f32x4){0.f,0.f,0.f,0.f};
  }

  f32x4 acc[4][2];
#pragma unroll
  for (int g = 0; g < 4; ++g)
#pragma unroll
    for (int ns = 0; ns < 2; ++ns)
      acc[g][ns] = (f32x4){0.f, 0.f, 0.f, 0.f};

  __syncthreads();   // drains vmcnt(0): staging + c load complete

  // ---- tap loop: fully unrolled, single fp16 precision ----
#pragma unroll
  for (int tap = 0; tap < 9; ++tap){
    const int ky = tap / 3;
    const int kx = tap - ky*3;
    const int r0 = wy + ky;             // staged row index 0..5
    const int ps = kx + nn;

    // x2h: weights (global, L2-resident) + x fragments (LDS)
    {
      const unsigned short* wp = wxT + (size_t)(tap*4 + chunk)*2048 + wfo;
      f16x8 ax[4];
#pragma unroll
      for (int g = 0; g < 4; ++g) ax[g] = *(const f16x8*)(wp + g*512);
      f16x8 bxf[2];   // [ns]
#pragma unroll
      for (int ns = 0; ns < 2; ++ns)
        bxf[ns] = *(const f16x8*)&xs[r0*LROW + (q*34 + ns*16 + ps)*8];
      __builtin_amdgcn_s_setprio(1);
#pragma unroll
      for (int ns = 0; ns < 2; ++ns)
#pragma unroll
        for (int g = 0; g < 4; ++g)
          acc[g][ns] = MFMA(ax[g], bxf[ns], acc[g][ns]);
      __builtin_amdgcn_s_setprio(0);
    }

    // h2h
    if (!FIRST){
      const unsigned short* hpw = whT + (size_t)(tap*4 + chunk)*4096 + wfo;
      f16x8 ah[2][4];
#pragma unroll
      for (int kc = 0; kc < 2; ++kc)
#pragma unroll
        for (int g = 0; g < 4; ++g) ah[kc][g] = *(const f16x8*)(hpw + kc*2048 + g*512);
      f16x8 bhf[2][2];   // [kc][ns]
#pragma unroll
      for (int kc = 0; kc < 2; ++kc)
#pragma unroll
        for (int ns = 0; ns < 2; ++ns)
          bhf[kc][ns] = *(const f16x8*)&hs[(r0*2 + kc)*LROW + (q*34 + ns*16 + ps)*8];
      __builtin_amdgcn_s_setprio(1);
#pragma unroll
      for (int kc = 0; kc < 2; ++kc)
#pragma unroll
        for (int ns = 0; ns < 2; ++ns)
#pragma unroll
          for (int g = 0; g < 4; ++g)
            acc[g][ns] = MFMA(ah[kc][g], bhf[kc][ns], acc[g][ns]);
      __builtin_amdgcn_s_setprio(0);
    }
  }

  // ---- epilogue: LSTM update, register-local ----
  // D layout: col = lane&15 = n (x), row = q*4 + r (hid within chunk)
  f32x4 bv[4];
#pragma unroll
  for (int g = 0; g < 4; ++g){
    f32x4 ba = *(const f32x4*)&bxb[g*HID + m0 + 4*q];
    f32x4 bb = *(const f32x4*)&bhb[g*HID + m0 + 4*q];
    bv[g] = ba + bb;
  }
  const int kcE = chunk >> 1;                       // h-layout indices for this
  const int qhE = ((chunk & 1) << 1) | (q >> 1);    // lane's 4 hid values
  const int c8b = (q & 1) * 4;
#pragma unroll
  for (int ns = 0; ns < 2; ++ns){
    const int xg = xh*32 + ns*16 + nn;
    f32x4 cn;
    float hn[4];
#pragma unroll
    for (int r = 0; r < 4; ++r){
      float iv = sigmoidf_(acc[0][ns][r] + bv[0][r]);
      float fv = sigmoidf_(acc[1][ns][r] + bv[1][r]);
      float gv = tanhf_  (acc[2][ns][r] + bv[2][r]);
      float ov = sigmoidf_(acc[3][ns][r] + bv[3][r]);
      float cnv = fv*cpre[ns][r] + iv*gv;
      cn[r] = cnv;
      hn[r] = ov * tanhf_(cnv);
    }
    *(f32x4*)&c_state[cslot + ns*4] = cn;
#pragma unroll
    for (int r = 0; r < 4; ++r)
      h_out[(((size_t)b*HID + m0 + 4*q + r)*HW + y)*HW + xg] = hn[r];
    const size_t hoff = ((size_t)b*PW + (y+1))*HROW + (kcE*4 + qhE)*QS + (xg+1)*8 + c8b;
    u16x4 ph;
#pragma unroll
    for (int r = 0; r < 4; ++r) ph[r] = f2h(hn[r]);
    *(u16x4*)&hc[hoff] = ph;
  }
}

// ---------------- fallback: fp32 kernel (verified round 3) ----------------

#define FCHUNK  8
#define FTILE_H 16
#define FROWS   (FTILE_H + 2)
#define FSTRIDE 68

__device__ __forceinline__ void do_chunk_f(
    float tile[FCHUNK][FROWS][FSTRIDE],
    const float* __restrict__ src,
    const float* __restrict__ wp0, const float* __restrict__ wp1,
    const float* __restrict__ wp2, const float* __restrict__ wp3,
    int gy0, int txg, int ty, int tid, float (&acc)[4][2][4])
{
  __syncthreads();
  for (int s = tid; s < FCHUNK * FROWS * 32; s += 128) {
    int c2 = s & 31;
    int rowid = s >> 5;
    int ic = rowid / FROWS;
    int r  = rowid - ic * FROWS;
    int gy = gy0 - 1 + r;
    if ((unsigned)gy < (unsigned)HW) {
      float2 v = *(const float2*)&src[(ic << 12) + (gy << 6) + (c2 << 1)];
      *(float2*)&tile[ic][r][2 + (c2 << 1)] = v;
    }
  }
  __syncthreads();
  for (int ic = 0; ic < FCHUNK; ++ic) {
    float w0[9], w1[9], w2[9], w3[9];
#pragma unroll
    for (int k = 0; k < 9; ++k) {
      w0[k] = wp0[ic*9+k]; w1[k] = wp1[ic*9+k];
      w2[k] = wp2[ic*9+k]; w3[k] = wp3[ic*9+k];
    }
    float rv[4][8];
#pragma unroll
    for (int rr = 0; rr < 4; ++rr) {
      const float* p = &tile[ic][2*ty+rr][4*txg];
      float4 a  = *(const float4*)p;
      float4 bb = *(const float4*)(p + 4);
      rv[rr][0]=a.x; rv[rr][1]=a.y; rv[rr][2]=a.z; rv[rr][3]=a.w;
      rv[rr][4]=bb.x; rv[rr][5]=bb.y; rv[rr][6]=bb.z; rv[rr][7]=bb.w;
    }
#pragma unroll
    for (int j = 0; j < 2; ++j)
#pragma unroll
      for (int dy = 0; dy < 3; ++dy)
#pragma unroll
        for (int qq = 0; qq < 4; ++qq)
#pragma unroll
          for (int dx = 0; dx < 3; ++dx) {
            float v = rv[j+dy][qq+dx+1];
            int k = dy*3+dx;
            acc[0][j][qq] = fmaf(v, w0[k], acc[0][j][qq]);
            acc[1][j][qq] = fmaf(v, w1[k], acc[1][j][qq]);
            acc[2][j][qq] = fmaf(v, w2[k], acc[2][j][qq]);
            acc[3][j][qq] = fmaf(v, w3[k], acc[3][j][qq]);
          }
  }
}

__global__ __launch_bounds__(128) void convlstm_step_f(
    const float* __restrict__ x_t, const float* __restrict__ h_prev,
    const float* __restrict__ w_x2h, const float* __restrict__ b_x2h,
    const float* __restrict__ w_h2h, const float* __restrict__ b_h2h,
    float* __restrict__ c_state, float* __restrict__ h_out, int first)
{
  __shared__ float tile[FCHUNK][FROWS][FSTRIDE];
  const int txg = threadIdx.x, ty = threadIdx.y;
  const int tid = ty*16 + txg;
  const int by = blockIdx.x, hc = blockIdx.y, b = blockIdx.z;
  const int gy0 = by * FTILE_H;
  {
    float2* p = (float2*)&tile[0][0][0];
    for (int i = tid; i < FCHUNK*FROWS*FSTRIDE/2; i += 128)
      p[i] = make_float2(0.f, 0.f);
  }
  float acc[4][2][4];
#pragma unroll
  for (int g = 0; g < 4; ++g)
#pragma unroll
    for (int j = 0; j < 2; ++j)
#pragma unroll
      for (int qq = 0; qq < 4; ++qq) acc[g][j][qq] = 0.f;
  {
    const float* wx0 = w_x2h + (size_t)(0*HID+hc)*CX*9;
    const float* wx1 = w_x2h + (size_t)(1*HID+hc)*CX*9;
    const float* wx2 = w_x2h + (size_t)(2*HID+hc)*CX*9;
    const float* wx3 = w_x2h + (size_t)(3*HID+hc)*CX*9;
    for (int c0 = 0; c0 < CX; c0 += FCHUNK)
      do_chunk_f(tile, x_t + ((size_t)(b*CX+c0) << 12),
                 wx0+c0*9, wx1+c0*9, wx2+c0*9, wx3+c0*9, gy0, txg, ty, tid, acc);
  }
  if (!first){
    const float* wh0 = w_h2h + (size_t)(0*HID+hc)*HID*9;
    const float* wh1 = w_h2h + (size_t)(1*HID+hc)*HID*9;
    const float* wh2 = w_h2h + (size_t)(2*HID+hc)*HID*9;
    const float* wh3 = w_h2h + (size_t)(3*HID+hc)*HID*9;
    for (int c0 = 0; c0 < HID; c0 += FCHUNK)
      do_chunk_f(tile, h_prev + ((size_t)(b*HID+c0) << 12),
                 wh0+c0*9, wh1+c0*9, wh2+c0*9, wh3+c0*9, gy0, txg, ty, tid, acc);
  }
  const float bi = b_x2h[0*HID+hc] + b_h2h[0*HID+hc];
  const float bf = b_x2h[1*HID+hc] + b_h2h[1*HID+hc];
  const float bg = b_x2h[2*HID+hc] + b_h2h[2*HID+hc];
  const float bo = b_x2h[3*HID+hc] + b_h2h[3*HID+hc];
#pragma unroll
  for (int j = 0; j < 2; ++j){
    const int row = gy0 + 2*ty + j;
    const int off = ((b*HID + hc)*HW + row)*HW + 4*txg;
    float4 cpv4 = make_float4(0.f,0.f,0.f,0.f);
    if (!first) cpv4 = *(const float4*)&c_state[off];
    float cn[4], hn[4];
    const float cpv[4] = {cpv4.x, cpv4.y, cpv4.z, cpv4.w};
#pragma unroll
    for (int qq = 0; qq < 4; ++qq){
      const float ig = sigmoidf_(acc[0][j][qq] + bi);
      const float fg = sigmoidf_(acc[1][j][qq] + bf);
      const float gg = tanhf_  (acc[2][j][qq] + bg);
      const float og = sigmoidf_(acc[3][j][qq] + bo);
      const float cnv = fg*cpv[qq] + ig*gg;
      cn[qq] = cnv;
      hn[qq] = og * tanhf_(cnv);
    }
    *(float4*)&c_state[off] = make_float4(cn[0],cn[1],cn[2],cn[3]);
    *(float4*)&h_out[off]   = make_float4(hn[0],hn[1],hn[2],hn[3]);
  }
}

// ---------------- launcher ----------------

extern "C" void kernel_launch(void* const* d_in, const int* in_sizes, int n_in,
                              void* d_out, int out_size, void* d_ws, size_t ws_size,
                              hipStream_t stream) {
  const float* x     = (const float*)d_in[0];
  const float* w_x2h = (const float*)d_in[1];
  const float* b_x2h = (const float*)d_in[2];
  const float* w_h2h = (const float*)d_in[3];
  const float* b_h2h = (const float*)d_in[4];
  float* out = (float*)d_out;

  // ws layout (256-aligned)
  size_t off = 0;
  auto alloc = [&](size_t bytes) -> char* {
    char* p = (char*)d_ws + off;
    off += (bytes + 255) & ~(size_t)255;
    return p;
  };
  float* c_state = (float*)alloc((size_t)256*512*8*4);                // 4 MB
  unsigned short* wxT = (unsigned short*)alloc((size_t)9*4*2048*2);   // 147 KB
  unsigned short* whT = (unsigned short*)alloc((size_t)9*4*4096*2);   // 295 KB
  const size_t hT_bytes = (size_t)BATCH*PW*HROW*2;                    // 2,230,272
  unsigned short* hA = (unsigned short*)alloc(hT_bytes);
  unsigned short* hB = (unsigned short*)alloc(hT_bytes);
  const size_t xT_bytes = (size_t)TSTEPS*BATCH*PW*XROW*2;             // 17,842,176
  unsigned short* xT = (unsigned short*)alloc(xT_bytes);
  const size_t need = off;

  const size_t x_step = (size_t)BATCH*CX*HW*HW;
  const size_t h_step = (size_t)BATCH*HID*HW*HW;

  if (need <= ws_size) {
    // ---- MFMA fp16 path ----
    prep_w<<<(9*256*HID + 255)/256, 256, 0, stream>>>(w_x2h, w_h2h, wxT, whT);
    prep_x<<<dim3(TSTEPS*BATCH, PW), 256, 0, stream>>>(x, xT);
    zero_ws<<<1024, 256, 0, stream>>>((unsigned long long*)hA, 2*hT_bytes/8);

    for (int t = 0; t < TSTEPS; ++t) {
      unsigned short* hp = (t & 1) ? hA : hB;
      unsigned short* hc = (t & 1) ? hB : hA;
      if (t == 0)
        step_mfma<1><<<dim3(4, 16, BATCH), 512, 0, stream>>>(
            xT, wxT, whT, hp, hc, b_x2h, b_h2h,
            c_state, out + (size_t)t*h_step, t);
      else
        step_mfma<0><<<dim3(4, 16, BATCH), 512, 0, stream>>>(
            xT, wxT, whT, hp, hc, b_x2h, b_h2h,
            c_state, out + (size_t)t*h_step, t);
    }
  } else {
    // ---- fallback fp32 path ----
    dim3 grid(HW / FTILE_H, HID, BATCH);
    dim3 block(16, 8);
    for (int t = 0; t < TSTEPS; ++t) {
      const float* x_t    = x + (size_t)t*x_step;
      const float* h_prev = (t == 0) ? x : out + (size_t)(t-1)*h_step;
      float* h_out        = out + (size_t)t*h_step;
      convlstm_step_f<<<grid, block, 0, stream>>>(
          x_t, h_prev, w_x2h, b_x2h, w_h2h, b_h2h, c_state, h_out, t == 0 ? 1 : 0);
    }
  }
}